// Round 1
// baseline (126.933 us; speedup 1.0000x reference)
//
#include <hip/hip_runtime.h>
#include <math.h>

// Constants from the reference
#define COEF 14.399645478425668f
#define EPSF 1e-8f
#define SQRT_2LOG 6.069708847f        // sqrt(-2 ln 1e-8)
#define INV_SQRT_2PI 0.3989422804014327f
#define TWO_PI 6.283185307179586f
#define SQRT_2_OVER_PI 0.7978845608028654f
#define INV_SQRT_PI 0.5641895835477563f

// Compute volume, eta, and inverse cell from the 3x3 cell (row-major).
__device__ inline void cell_derived(const float* __restrict__ cell, int n,
                                    float& volume, float& eta, float M[3][3]) {
    float a00 = cell[0], a01 = cell[1], a02 = cell[2];
    float a10 = cell[3], a11 = cell[4], a12 = cell[5];
    float a20 = cell[6], a21 = cell[7], a22 = cell[8];
    float c00 = a11 * a22 - a12 * a21;
    float c01 = a12 * a20 - a10 * a22;
    float c02 = a10 * a21 - a11 * a20;
    float det = a00 * c00 + a01 * c01 + a02 * c02;
    volume = fabsf(det);
    eta = powf(volume * volume / (float)n, 1.0f / 6.0f) * INV_SQRT_2PI;
    float invdet = 1.0f / det;
    M[0][0] =  (a11 * a22 - a12 * a21) * invdet;
    M[0][1] = -(a01 * a22 - a02 * a21) * invdet;
    M[0][2] =  (a01 * a12 - a02 * a11) * invdet;
    M[1][0] = -(a10 * a22 - a12 * a20) * invdet;
    M[1][1] =  (a00 * a22 - a02 * a20) * invdet;
    M[1][2] = -(a00 * a12 - a02 * a10) * invdet;
    M[2][0] =  (a10 * a21 - a11 * a20) * invdet;
    M[2][1] = -(a00 * a21 - a01 * a20) * invdet;
    M[2][2] =  (a00 * a11 - a01 * a10) * invdet;
}

__global__ void zero_acc_kernel(double* acc) {
    if (threadIdx.x == 0 && blockIdx.x == 0) acc[0] = 0.0;
}

// Real-space sum: one thread per (i,j) pair, loop over shifts.
__global__ void ewald_real_kernel(const float* __restrict__ pos,
                                  const float* __restrict__ cell,
                                  const float* __restrict__ charges,
                                  const float* __restrict__ sigma_table,
                                  const int* __restrict__ species,
                                  const int* __restrict__ p_nr,
                                  int n, double* __restrict__ acc) {
    extern __shared__ float sm[];
    float* px = sm;          // n
    float* py = sm + n;      // n
    float* pz = sm + 2 * n;  // n
    float* sq = sm + 3 * n;  // n
    float* s2 = sm + 4 * n;  // n (sigma^2)
    float* red = sm + 5 * n; // reduction scratch (>= waves/block)

    for (int t = threadIdx.x; t < n; t += blockDim.x) {
        px[t] = pos[3 * t + 0];
        py[t] = pos[3 * t + 1];
        pz[t] = pos[3 * t + 2];
        sq[t] = charges[t];
        float s = sigma_table[species[t]];
        s2[t] = s * s;
    }
    __syncthreads();

    int nr = p_nr[0];
    float vol, eta, M[3][3];
    cell_derived(cell, n, vol, eta, M);
    float cutoff = SQRT_2LOG * eta;
    float cut2 = cutoff * cutoff;
    float inv_s2eta = 1.0f / (1.41421356237f * eta);
    // hoist cell rows
    float c00 = cell[0], c01 = cell[1], c02 = cell[2];
    float c10 = cell[3], c11 = cell[4], c12 = cell[5];
    float c20 = cell[6], c21 = cell[7], c22 = cell[8];

    float thr_acc = 0.0f;
    long long total = (long long)n * n;
    long long stride = (long long)gridDim.x * blockDim.x;
    for (long long p = (long long)blockIdx.x * blockDim.x + threadIdx.x; p < total; p += stride) {
        int i = (int)(p / n);
        int j = (int)(p - (long long)i * n);
        float dx = px[j] - px[i];
        float dy = py[j] - py[i];
        float dz = pz[j] - pz[i];
        float gam2 = s2[i] + s2[j];
        float inv_s2gam = rsqrtf(2.0f * gam2);
        float pacc = 0.0f;
        for (int a = -nr; a <= nr; ++a) {
            for (int b = -nr; b <= nr; ++b) {
                for (int c = -nr; c <= nr; ++c) {
                    float hx = a * c00 + b * c10 + c * c20;
                    float hy = a * c01 + b * c11 + c * c21;
                    float hz = a * c02 + b * c12 + c * c22;
                    float ddx = dx + hx, ddy = dy + hy, ddz = dz + hz;
                    float r2 = ddx * ddx + ddy * ddy + ddz * ddz;
                    if (r2 > EPSF * EPSF && r2 < cut2) {
                        float r = sqrtf(r2);
                        pacc += (erfcf(r * inv_s2eta) - erfcf(r * inv_s2gam)) / r;
                    }
                }
            }
        }
        thr_acc += pacc * sq[i] * sq[j];
    }

    // wave + block reduce
    float v = thr_acc;
    #pragma unroll
    for (int off = 32; off > 0; off >>= 1) v += __shfl_down(v, off);
    int wave = threadIdx.x >> 6, lane = threadIdx.x & 63;
    if (lane == 0) red[wave] = v;
    __syncthreads();
    if (threadIdx.x == 0) {
        float tot = 0.0f;
        int nw = blockDim.x >> 6;
        for (int w = 0; w < nw; ++w) tot += red[w];
        atomicAdd(acc, (double)tot * (double)(0.5f * COEF));
    }
}

// Reciprocal-space sum via structure factors: one wave per k-vector,
// 64 lanes split the atoms.
__global__ void ewald_recip_kernel(const float* __restrict__ pos,
                                   const float* __restrict__ cell,
                                   const float* __restrict__ charges,
                                   const int* __restrict__ p_nk,
                                   int n, double* __restrict__ acc) {
    extern __shared__ float sm[];
    float* px = sm;
    float* py = sm + n;
    float* pz = sm + 2 * n;
    float* sq = sm + 3 * n;
    float* red = sm + 4 * n;

    for (int t = threadIdx.x; t < n; t += blockDim.x) {
        px[t] = pos[3 * t + 0];
        py[t] = pos[3 * t + 1];
        pz[t] = pos[3 * t + 2];
        sq[t] = charges[t];
    }
    __syncthreads();

    int nk = p_nk[0];
    int side = 2 * nk + 1;
    int K = side * side * side;
    float vol, eta, M[3][3];
    cell_derived(cell, n, vol, eta, M);
    float cutk = SQRT_2LOG / eta;
    float half_eta2 = 0.5f * eta * eta;

    int lane = threadIdx.x & 63;
    int wave = threadIdx.x >> 6;
    int waves_per_block = blockDim.x >> 6;
    int gwave = blockIdx.x * waves_per_block + wave;
    int nwaves = gridDim.x * waves_per_block;

    float lacc = 0.0f;
    for (int k = gwave; k < K; k += nwaves) {
        int a = k / (side * side) - nk;
        int rem = k % (side * side);
        int b = rem / side - nk;
        int c = rem % side - nk;
        float kx = TWO_PI * (M[0][0] * a + M[0][1] * b + M[0][2] * c);
        float ky = TWO_PI * (M[1][0] * a + M[1][1] * b + M[1][2] * c);
        float kz = TWO_PI * (M[2][0] * a + M[2][1] * b + M[2][2] * c);
        float k2 = kx * kx + ky * ky + kz * kz;
        float klen = sqrtf(k2);
        if (!(klen > EPSF && klen < cutk)) continue;
        float w = __expf(-half_eta2 * k2) / k2;
        float Sc = 0.0f, Ss = 0.0f;
        for (int i = lane; i < n; i += 64) {
            float th = kx * px[i] + ky * py[i] + kz * pz[i];
            float sv, cv;
            __sincosf(th, &sv, &cv);
            float q = sq[i];
            Sc += q * cv;
            Ss += q * sv;
        }
        #pragma unroll
        for (int off = 32; off > 0; off >>= 1) {
            Sc += __shfl_down(Sc, off);
            Ss += __shfl_down(Ss, off);
        }
        if (lane == 0) lacc += w * (Sc * Sc + Ss * Ss);
    }

    // lacc is nonzero only on lane 0 of each wave
    if (lane == 0) red[wave] = lacc;
    __syncthreads();
    if (threadIdx.x == 0) {
        float tot = 0.0f;
        int nw = blockDim.x >> 6;
        for (int w = 0; w < nw; ++w) tot += red[w];
        double scale = 0.5 * (double)COEF * (4.0 * 3.14159265358979323846 / (double)vol);
        atomicAdd(acc, (double)tot * scale);
    }
}

// Self term + final write. Runs after real/recip (stream-ordered).
__global__ void ewald_self_final_kernel(const float* __restrict__ cell,
                                        const float* __restrict__ charges,
                                        const float* __restrict__ sigma_table,
                                        const int* __restrict__ species,
                                        int n, const double* __restrict__ acc,
                                        float* __restrict__ out) {
    __shared__ float red[8];
    float vol, eta, M[3][3];
    cell_derived(cell, n, vol, eta, M);

    float ds = 0.0f;
    for (int i = threadIdx.x; i < n; i += blockDim.x) {
        float s = sigma_table[species[i]];
        float q = charges[i];
        float diag = -SQRT_2_OVER_PI / eta + INV_SQRT_PI / s;
        ds += 0.5f * COEF * q * q * diag;
    }
    float v = ds;
    #pragma unroll
    for (int off = 32; off > 0; off >>= 1) v += __shfl_down(v, off);
    int wave = threadIdx.x >> 6, lane = threadIdx.x & 63;
    if (lane == 0) red[wave] = v;
    __syncthreads();
    if (threadIdx.x == 0) {
        float tot = 0.0f;
        int nw = blockDim.x >> 6;
        for (int w = 0; w < nw; ++w) tot += red[w];
        out[0] = (float)(acc[0] + (double)tot);
    }
}

extern "C" void kernel_launch(void* const* d_in, const int* in_sizes, int n_in,
                              void* d_out, int out_size, void* d_ws, size_t ws_size,
                              hipStream_t stream) {
    const float* pos         = (const float*)d_in[0];
    const float* cell        = (const float*)d_in[1];
    const float* charges     = (const float*)d_in[2];
    const float* sigma_table = (const float*)d_in[3];
    const int*   species     = (const int*)d_in[4];
    const int*   p_nr        = (const int*)d_in[5];
    const int*   p_nk        = (const int*)d_in[6];
    int n = in_sizes[0] / 3;

    double* acc = (double*)d_ws;
    float* out = (float*)d_out;

    zero_acc_kernel<<<1, 64, 0, stream>>>(acc);

    // real-space: one thread per (i,j) pair
    long long pairs = (long long)n * n;
    int real_blocks = (int)((pairs + 255) / 256);
    if (real_blocks > 4096) real_blocks = 4096;
    size_t sm_real = (size_t)(5 * n + 16) * sizeof(float);
    ewald_real_kernel<<<real_blocks, 256, sm_real, stream>>>(
        pos, cell, charges, sigma_table, species, p_nr, n, acc);

    // recip-space: one wave per k-vector (nk=8 -> 4913 waves -> 1229 blocks)
    size_t sm_recip = (size_t)(4 * n + 16) * sizeof(float);
    ewald_recip_kernel<<<1232, 256, sm_recip, stream>>>(
        pos, cell, charges, p_nk, n, acc);

    ewald_self_final_kernel<<<1, 256, 0, stream>>>(
        cell, charges, sigma_table, species, n, acc, out);
}

// Round 2
// 93.935 us; speedup vs baseline: 1.3513x; 1.3513x over previous
//
#include <hip/hip_runtime.h>
#include <math.h>

#define COEF 14.399645478425668f
#define EPS2F 1e-16f
#define SQRT_2LOG 6.069708847f        // sqrt(-2 ln 1e-8)
#define INV_SQRT_2PI 0.3989422804014327f
#define TWO_PI 6.283185307179586f
#define INV_TWO_PI 0.15915494309189535f
#define SQRT_2_OVER_PI 0.7978845608028654f
#define INV_SQRT_PI 0.5641895835477563f

// Fast erfc: Abramowitz-Stegun 7.1.26, x >= 0, abs err < 1.5e-7.
__device__ inline float erfc_fast(float x) {
    float t = 1.0f / fmaf(0.3275911f, x, 1.0f);
    float p = fmaf(t, 1.061405429f, -1.453152027f);
    p = fmaf(t, p, 1.421413741f);
    p = fmaf(t, p, -0.284496736f);
    p = fmaf(t, p, 0.254829592f);
    p *= t;
    return p * __expf(-x * x);
}

__device__ inline void cell_derived(const float* __restrict__ cell, int n,
                                    float& volume, float& eta, float M[3][3]) {
    float a00 = cell[0], a01 = cell[1], a02 = cell[2];
    float a10 = cell[3], a11 = cell[4], a12 = cell[5];
    float a20 = cell[6], a21 = cell[7], a22 = cell[8];
    float c00 = a11 * a22 - a12 * a21;
    float c01 = a12 * a20 - a10 * a22;
    float c02 = a10 * a21 - a11 * a20;
    float det = a00 * c00 + a01 * c01 + a02 * c02;
    volume = fabsf(det);
    eta = powf(volume * volume / (float)n, 1.0f / 6.0f) * INV_SQRT_2PI;
    float invdet = 1.0f / det;
    M[0][0] =  (a11 * a22 - a12 * a21) * invdet;
    M[0][1] = -(a01 * a22 - a02 * a21) * invdet;
    M[0][2] =  (a01 * a12 - a02 * a11) * invdet;
    M[1][0] = -(a10 * a22 - a12 * a20) * invdet;
    M[1][1] =  (a00 * a22 - a02 * a20) * invdet;
    M[1][2] = -(a00 * a12 - a02 * a10) * invdet;
    M[2][0] =  (a10 * a21 - a11 * a20) * invdet;
    M[2][1] = -(a00 * a21 - a01 * a20) * invdet;
    M[2][2] =  (a00 * a11 - a01 * a10) * invdet;
}

__global__ void zero_acc_kernel(double* acc) {
    if (threadIdx.x == 0 && blockIdx.x == 0) acc[0] = 0.0;
}

// Fused real+recip. Blocks [0, real_blocks) do the real-space triangular
// pair sum; blocks [real_blocks, gridDim.x) do the reciprocal sum.
__global__ void ewald_fused_kernel(const float* __restrict__ pos,
                                   const float* __restrict__ cell,
                                   const float* __restrict__ charges,
                                   const float* __restrict__ sigma_table,
                                   const int* __restrict__ species,
                                   const int* __restrict__ p_nr,
                                   const int* __restrict__ p_nk,
                                   int n, int real_blocks,
                                   double* __restrict__ acc) {
    extern __shared__ float sm[];
    float* px = sm;
    float* py = sm + n;
    float* pz = sm + 2 * n;
    float* sq = sm + 3 * n;
    float* s2 = sm + 4 * n;
    float* red = sm + 5 * n;  // 8 floats

    for (int t = threadIdx.x; t < n; t += blockDim.x) {
        px[t] = pos[3 * t + 0];
        py[t] = pos[3 * t + 1];
        pz[t] = pos[3 * t + 2];
        sq[t] = charges[t];
        float s = sigma_table[species[t]];
        s2[t] = s * s;
    }
    __syncthreads();

    float vol, eta, M[3][3];
    cell_derived(cell, n, vol, eta, M);

    int lane = threadIdx.x & 63;
    int wave = threadIdx.x >> 6;
    float thr_acc = 0.0f;   // scaled per-part before atomic
    double scale;

    if (blockIdx.x < real_blocks) {
        // ---------- real space ----------
        int nr = p_nr[0];
        float cutoff = SQRT_2LOG * eta;
        float cut2 = cutoff * cutoff;
        float inv_s2eta = 1.0f / (1.41421356237f * eta);
        float c00 = cell[0], c01 = cell[1], c02 = cell[2];
        float c10 = cell[3], c11 = cell[4], c12 = cell[5];
        float c20 = cell[6], c21 = cell[7], c22 = cell[8];

        long long T = (long long)n * (n + 1) / 2;
        long long p = (long long)blockIdx.x * blockDim.x + threadIdx.x;
        if (p < T) {
            // triangular decode: i >= j
            float fp = 8.0f * (float)p + 1.0f;
            int i = (int)((sqrtf(fp) - 1.0f) * 0.5f);
            while ((long long)i * (i + 1) / 2 > p) --i;
            while ((long long)(i + 1) * (i + 2) / 2 <= p) ++i;
            int j = (int)(p - (long long)i * (i + 1) / 2);

            float dx = px[j] - px[i];
            float dy = py[j] - py[i];
            float dz = pz[j] - pz[i];
            float gam2 = s2[i] + s2[j];
            float inv_s2gam = rsqrtf(2.0f * gam2);
            float pacc = 0.0f;

            if (nr == 1) {
                #pragma unroll
                for (int a = -1; a <= 1; ++a) {
                    #pragma unroll
                    for (int b = -1; b <= 1; ++b) {
                        #pragma unroll
                        for (int c = -1; c <= 1; ++c) {
                            float ddx = dx + a * c00 + b * c10 + c * c20;
                            float ddy = dy + a * c01 + b * c11 + c * c21;
                            float ddz = dz + a * c02 + b * c12 + c * c22;
                            float r2 = fmaf(ddx, ddx, fmaf(ddy, ddy, ddz * ddz));
                            bool in = (r2 > EPS2F) & (r2 < cut2);
                            float r2s = in ? r2 : 1.0f;
                            float m = in ? 1.0f : 0.0f;
                            float rinv = rsqrtf(r2s);
                            float r = r2s * rinv;
                            float v = (erfc_fast(r * inv_s2eta) -
                                       erfc_fast(r * inv_s2gam)) * rinv;
                            pacc = fmaf(v, m, pacc);
                        }
                    }
                }
            } else {
                for (int a = -nr; a <= nr; ++a)
                for (int b = -nr; b <= nr; ++b)
                for (int c = -nr; c <= nr; ++c) {
                    float ddx = dx + a * c00 + b * c10 + c * c20;
                    float ddy = dy + a * c01 + b * c11 + c * c21;
                    float ddz = dz + a * c02 + b * c12 + c * c22;
                    float r2 = fmaf(ddx, ddx, fmaf(ddy, ddy, ddz * ddz));
                    bool in = (r2 > EPS2F) & (r2 < cut2);
                    float r2s = in ? r2 : 1.0f;
                    float m = in ? 1.0f : 0.0f;
                    float rinv = rsqrtf(r2s);
                    float r = r2s * rinv;
                    float v = (erfc_fast(r * inv_s2eta) -
                               erfc_fast(r * inv_s2gam)) * rinv;
                    pacc = fmaf(v, m, pacc);
                }
            }
            float w = (i == j) ? 1.0f : 2.0f;
            thr_acc = pacc * sq[i] * sq[j] * w;
        }
        scale = 0.5 * (double)COEF;
    } else {
        // ---------- reciprocal space ----------
        int nk = p_nk[0];
        int side = 2 * nk + 1;
        int K = side * side * side;
        float cutk = SQRT_2LOG / eta;
        float half_eta2 = 0.5f * eta * eta;

        int rb = blockIdx.x - real_blocks;
        int nrb = gridDim.x - real_blocks;
        int waves_per_block = blockDim.x >> 6;
        int gwave = rb * waves_per_block + wave;
        int nwaves = nrb * waves_per_block;

        for (int k = gwave; k < K; k += nwaves) {
            int a = k / (side * side) - nk;
            int rem = k % (side * side);
            int b = rem / side - nk;
            int c = rem % side - nk;
            float kx = TWO_PI * (M[0][0] * a + M[0][1] * b + M[0][2] * c);
            float ky = TWO_PI * (M[1][0] * a + M[1][1] * b + M[1][2] * c);
            float kz = TWO_PI * (M[2][0] * a + M[2][1] * b + M[2][2] * c);
            float k2 = fmaf(kx, kx, fmaf(ky, ky, kz * kz));
            float klen = sqrtf(k2);
            if (!(klen > 1e-8f && klen < cutk)) continue;
            float w = __expf(-half_eta2 * k2) / k2;
            float Sc = 0.0f, Ss = 0.0f;
            for (int i = lane; i < n; i += 64) {
                float th = fmaf(kx, px[i], fmaf(ky, py[i], kz * pz[i]));
                float sv, cv;
                __sincosf(th, &sv, &cv);
                float q = sq[i];
                Sc = fmaf(q, cv, Sc);
                Ss = fmaf(q, sv, Ss);
            }
            #pragma unroll
            for (int off = 32; off > 0; off >>= 1) {
                Sc += __shfl_down(Sc, off);
                Ss += __shfl_down(Ss, off);
            }
            if (lane == 0) thr_acc += w * (Sc * Sc + Ss * Ss);
        }
        scale = 0.5 * (double)COEF * (4.0 * 3.14159265358979323846 / (double)vol);
    }

    // block reduce (thr_acc already restricted to contributing lanes)
    float v = thr_acc;
    #pragma unroll
    for (int off = 32; off > 0; off >>= 1) v += __shfl_down(v, off);
    if (lane == 0) red[wave] = v;
    __syncthreads();
    if (threadIdx.x == 0) {
        float tot = 0.0f;
        int nw = blockDim.x >> 6;
        for (int w = 0; w < nw; ++w) tot += red[w];
        if (tot != 0.0f) atomicAdd(acc, (double)tot * scale);
    }
}

// Self term + final write (stream-ordered after fused kernel).
__global__ void ewald_self_final_kernel(const float* __restrict__ cell,
                                        const float* __restrict__ charges,
                                        const float* __restrict__ sigma_table,
                                        const int* __restrict__ species,
                                        int n, const double* __restrict__ acc,
                                        float* __restrict__ out) {
    __shared__ float red[8];
    float vol, eta, M[3][3];
    cell_derived(cell, n, vol, eta, M);

    float ds = 0.0f;
    for (int i = threadIdx.x; i < n; i += blockDim.x) {
        float s = sigma_table[species[i]];
        float q = charges[i];
        float diag = -SQRT_2_OVER_PI / eta + INV_SQRT_PI / s;
        ds += 0.5f * COEF * q * q * diag;
    }
    float v = ds;
    #pragma unroll
    for (int off = 32; off > 0; off >>= 1) v += __shfl_down(v, off);
    int wave = threadIdx.x >> 6, lane = threadIdx.x & 63;
    if (lane == 0) red[wave] = v;
    __syncthreads();
    if (threadIdx.x == 0) {
        float tot = 0.0f;
        int nw = blockDim.x >> 6;
        for (int w = 0; w < nw; ++w) tot += red[w];
        out[0] = (float)(acc[0] + (double)tot);
    }
}

extern "C" void kernel_launch(void* const* d_in, const int* in_sizes, int n_in,
                              void* d_out, int out_size, void* d_ws, size_t ws_size,
                              hipStream_t stream) {
    const float* pos         = (const float*)d_in[0];
    const float* cell        = (const float*)d_in[1];
    const float* charges     = (const float*)d_in[2];
    const float* sigma_table = (const float*)d_in[3];
    const int*   species     = (const int*)d_in[4];
    const int*   p_nr        = (const int*)d_in[5];
    const int*   p_nk        = (const int*)d_in[6];
    int n = in_sizes[0] / 3;

    double* acc = (double*)d_ws;
    float* out = (float*)d_out;

    zero_acc_kernel<<<1, 64, 0, stream>>>(acc);

    long long T = (long long)n * (n + 1) / 2;
    int real_blocks = (int)((T + 255) / 256);
    int recip_blocks = 308;
    int total_blocks = real_blocks + recip_blocks;
    size_t sm_bytes = (size_t)(5 * n + 16) * sizeof(float);

    ewald_fused_kernel<<<total_blocks, 256, sm_bytes, stream>>>(
        pos, cell, charges, sigma_table, species, p_nr, p_nk,
        n, real_blocks, acc);

    ewald_self_final_kernel<<<1, 256, 0, stream>>>(
        cell, charges, sigma_table, species, n, acc, out);
}

// Round 3
// 85.783 us; speedup vs baseline: 1.4797x; 1.0950x over previous
//
#include <hip/hip_runtime.h>
#include <math.h>

#define COEF 14.399645478425668f
#define EPS2F 1e-16f
#define SQRT_2LOG 6.069708847f        // sqrt(-2 ln 1e-8)
#define INV_SQRT_2PI 0.3989422804014327f
#define TWO_PI 6.283185307179586f
#define SQRT_2_OVER_PI 0.7978845608028654f
#define INV_SQRT_PI 0.5641895835477563f

// Fast erfc: Abramowitz-Stegun 7.1.26, x >= 0, abs err < 1.5e-7.
__device__ inline float erfc_fast(float x) {
    float t = 1.0f / fmaf(0.3275911f, x, 1.0f);
    float p = fmaf(t, 1.061405429f, -1.453152027f);
    p = fmaf(t, p, 1.421413741f);
    p = fmaf(t, p, -0.284496736f);
    p = fmaf(t, p, 0.254829592f);
    p *= t;
    return p * __expf(-x * x);
}

__device__ inline void cell_derived(const float* __restrict__ cell, int n,
                                    float& volume, float& eta, float M[3][3]) {
    float a00 = cell[0], a01 = cell[1], a02 = cell[2];
    float a10 = cell[3], a11 = cell[4], a12 = cell[5];
    float a20 = cell[6], a21 = cell[7], a22 = cell[8];
    float c00 = a11 * a22 - a12 * a21;
    float c01 = a12 * a20 - a10 * a22;
    float c02 = a10 * a21 - a11 * a20;
    float det = a00 * c00 + a01 * c01 + a02 * c02;
    volume = fabsf(det);
    eta = powf(volume * volume / (float)n, 1.0f / 6.0f) * INV_SQRT_2PI;
    float invdet = 1.0f / det;
    M[0][0] =  (a11 * a22 - a12 * a21) * invdet;
    M[0][1] = -(a01 * a22 - a02 * a21) * invdet;
    M[0][2] =  (a01 * a12 - a02 * a11) * invdet;
    M[1][0] = -(a10 * a22 - a12 * a20) * invdet;
    M[1][1] =  (a00 * a22 - a02 * a20) * invdet;
    M[1][2] = -(a00 * a12 - a02 * a10) * invdet;
    M[2][0] =  (a10 * a21 - a11 * a20) * invdet;
    M[2][1] = -(a00 * a21 - a01 * a20) * invdet;
    M[2][2] =  (a00 * a11 - a01 * a10) * invdet;
}

// Fused real+recip. Blocks [0, real_blocks) do the real-space triangular
// pair sum; blocks [real_blocks, gridDim.x) do the reciprocal sum.
// Each block writes its (already scaled) partial into partials[blockIdx.x];
// every slot is unconditionally written, so no zero-init is needed.
__global__ void ewald_fused_kernel(const float* __restrict__ pos,
                                   const float* __restrict__ cell,
                                   const float* __restrict__ charges,
                                   const float* __restrict__ sigma_table,
                                   const int* __restrict__ species,
                                   const int* __restrict__ p_nr,
                                   const int* __restrict__ p_nk,
                                   int n, int real_blocks,
                                   double* __restrict__ partials) {
    extern __shared__ float sm[];
    float* px = sm;
    float* py = sm + n;
    float* pz = sm + 2 * n;
    float* sq = sm + 3 * n;
    float* s2 = sm + 4 * n;
    float* red = sm + 5 * n;  // 8 floats

    for (int t = threadIdx.x; t < n; t += blockDim.x) {
        px[t] = pos[3 * t + 0];
        py[t] = pos[3 * t + 1];
        pz[t] = pos[3 * t + 2];
        sq[t] = charges[t];
        float s = sigma_table[species[t]];
        s2[t] = s * s;
    }
    __syncthreads();

    float vol, eta, M[3][3];
    cell_derived(cell, n, vol, eta, M);

    int lane = threadIdx.x & 63;
    int wave = threadIdx.x >> 6;
    float thr_acc = 0.0f;   // per-part sum, scaled at the end
    double scale;

    if (blockIdx.x < real_blocks) {
        // ---------- real space ----------
        int nr = p_nr[0];
        float cutoff = SQRT_2LOG * eta;
        float cut2 = cutoff * cutoff;
        float inv_s2eta = 1.0f / (1.41421356237f * eta);
        float c00 = cell[0], c01 = cell[1], c02 = cell[2];
        float c10 = cell[3], c11 = cell[4], c12 = cell[5];
        float c20 = cell[6], c21 = cell[7], c22 = cell[8];

        long long T = (long long)n * (n + 1) / 2;
        long long p = (long long)blockIdx.x * blockDim.x + threadIdx.x;
        if (p < T) {
            // triangular decode: i >= j
            float fp = 8.0f * (float)p + 1.0f;
            int i = (int)((sqrtf(fp) - 1.0f) * 0.5f);
            while ((long long)i * (i + 1) / 2 > p) --i;
            while ((long long)(i + 1) * (i + 2) / 2 <= p) ++i;
            int j = (int)(p - (long long)i * (i + 1) / 2);

            float dx = px[j] - px[i];
            float dy = py[j] - py[i];
            float dz = pz[j] - pz[i];
            float gam2 = s2[i] + s2[j];
            float inv_s2gam = rsqrtf(2.0f * gam2);
            float pacc = 0.0f;

            for (int a = -nr; a <= nr; ++a)
            for (int b = -nr; b <= nr; ++b)
            for (int c = -nr; c <= nr; ++c) {
                float ddx = dx + a * c00 + b * c10 + c * c20;
                float ddy = dy + a * c01 + b * c11 + c * c21;
                float ddz = dz + a * c02 + b * c12 + c * c22;
                float r2 = fmaf(ddx, ddx, fmaf(ddy, ddy, ddz * ddz));
                bool in = (r2 > EPS2F) & (r2 < cut2);
                // wave-level skip: only ~40-60% of shifts fire for any lane
                if (__any(in)) {
                    float r2s = in ? r2 : 1.0f;
                    float m = in ? 1.0f : 0.0f;
                    float rinv = rsqrtf(r2s);
                    float r = r2s * rinv;
                    float v = (erfc_fast(r * inv_s2eta) -
                               erfc_fast(r * inv_s2gam)) * rinv;
                    pacc = fmaf(v, m, pacc);
                }
            }
            float w = (i == j) ? 1.0f : 2.0f;
            thr_acc = pacc * sq[i] * sq[j] * w;
        }
        scale = 0.5 * (double)COEF;
    } else {
        // ---------- reciprocal space ----------
        int nk = p_nk[0];
        int side = 2 * nk + 1;
        int K = side * side * side;
        float cutk = SQRT_2LOG / eta;
        float half_eta2 = 0.5f * eta * eta;

        int rb = blockIdx.x - real_blocks;
        int nrb = gridDim.x - real_blocks;
        int waves_per_block = blockDim.x >> 6;
        int gwave = rb * waves_per_block + wave;
        int nwaves = nrb * waves_per_block;

        for (int k = gwave; k < K; k += nwaves) {
            int a = k / (side * side) - nk;
            int rem = k % (side * side);
            int b = rem / side - nk;
            int c = rem % side - nk;
            float kx = TWO_PI * (M[0][0] * a + M[0][1] * b + M[0][2] * c);
            float ky = TWO_PI * (M[1][0] * a + M[1][1] * b + M[1][2] * c);
            float kz = TWO_PI * (M[2][0] * a + M[2][1] * b + M[2][2] * c);
            float k2 = fmaf(kx, kx, fmaf(ky, ky, kz * kz));
            float klen = sqrtf(k2);
            if (!(klen > 1e-8f && klen < cutk)) continue;
            float w = __expf(-half_eta2 * k2) / k2;
            float Sc = 0.0f, Ss = 0.0f;
            for (int i = lane; i < n; i += 64) {
                float th = fmaf(kx, px[i], fmaf(ky, py[i], kz * pz[i]));
                float sv, cv;
                __sincosf(th, &sv, &cv);
                float q = sq[i];
                Sc = fmaf(q, cv, Sc);
                Ss = fmaf(q, sv, Ss);
            }
            #pragma unroll
            for (int off = 32; off > 0; off >>= 1) {
                Sc += __shfl_down(Sc, off);
                Ss += __shfl_down(Ss, off);
            }
            if (lane == 0) thr_acc += w * (Sc * Sc + Ss * Ss);
        }
        scale = 0.5 * (double)COEF * (4.0 * 3.14159265358979323846 / (double)vol);
    }

    // block reduce
    float v = thr_acc;
    #pragma unroll
    for (int off = 32; off > 0; off >>= 1) v += __shfl_down(v, off);
    if (lane == 0) red[wave] = v;
    __syncthreads();
    if (threadIdx.x == 0) {
        float tot = 0.0f;
        int nw = blockDim.x >> 6;
        for (int w = 0; w < nw; ++w) tot += red[w];
        partials[blockIdx.x] = (double)tot * scale;
    }
}

// Reduce block partials + self term, write the scalar output.
__global__ void ewald_final_kernel(const float* __restrict__ cell,
                                   const float* __restrict__ charges,
                                   const float* __restrict__ sigma_table,
                                   const int* __restrict__ species,
                                   int n, int nparts,
                                   const double* __restrict__ partials,
                                   float* __restrict__ out) {
    __shared__ double redd[8];
    float vol, eta, M[3][3];
    cell_derived(cell, n, vol, eta, M);

    double dsum = 0.0;
    for (int i = threadIdx.x; i < nparts; i += blockDim.x)
        dsum += partials[i];
    for (int i = threadIdx.x; i < n; i += blockDim.x) {
        float s = sigma_table[species[i]];
        float q = charges[i];
        float diag = -SQRT_2_OVER_PI / eta + INV_SQRT_PI / s;
        dsum += (double)(0.5f * COEF * q * q * diag);
    }
    double v = dsum;
    #pragma unroll
    for (int off = 32; off > 0; off >>= 1) v += __shfl_down(v, off);
    int wave = threadIdx.x >> 6, lane = threadIdx.x & 63;
    if (lane == 0) redd[wave] = v;
    __syncthreads();
    if (threadIdx.x == 0) {
        double tot = 0.0;
        int nw = blockDim.x >> 6;
        for (int w = 0; w < nw; ++w) tot += redd[w];
        out[0] = (float)tot;
    }
}

extern "C" void kernel_launch(void* const* d_in, const int* in_sizes, int n_in,
                              void* d_out, int out_size, void* d_ws, size_t ws_size,
                              hipStream_t stream) {
    const float* pos         = (const float*)d_in[0];
    const float* cell        = (const float*)d_in[1];
    const float* charges     = (const float*)d_in[2];
    const float* sigma_table = (const float*)d_in[3];
    const int*   species     = (const int*)d_in[4];
    const int*   p_nr        = (const int*)d_in[5];
    const int*   p_nk        = (const int*)d_in[6];
    int n = in_sizes[0] / 3;

    double* partials = (double*)d_ws;
    float* out = (float*)d_out;

    long long T = (long long)n * (n + 1) / 2;
    int real_blocks = (int)((T + 255) / 256);   // 1154 for n=768
    int recip_blocks = 308;
    int total_blocks = real_blocks + recip_blocks;
    size_t sm_bytes = (size_t)(5 * n + 16) * sizeof(float);

    ewald_fused_kernel<<<total_blocks, 256, sm_bytes, stream>>>(
        pos, cell, charges, sigma_table, species, p_nr, p_nk,
        n, real_blocks, partials);

    ewald_final_kernel<<<1, 256, 0, stream>>>(
        cell, charges, sigma_table, species, n, total_blocks, partials, out);
}

// Round 4
// 80.940 us; speedup vs baseline: 1.5682x; 1.0598x over previous
//
#include <hip/hip_runtime.h>
#include <math.h>

#define COEF 14.399645478425668f
#define EPS2F 1e-16f
#define SQRT_2LOG 6.069708847f        // sqrt(-2 ln 1e-8)
#define INV_SQRT_2PI 0.3989422804014327f
#define TWO_PI 6.283185307179586f
#define SQRT_2_OVER_PI 0.7978845608028654f
#define INV_SQRT_PI 0.5641895835477563f

// Fast erfc: Abramowitz-Stegun 7.1.26, x >= 0, abs err < 1.5e-7.
__device__ inline float erfc_fast(float x) {
    float t = 1.0f / fmaf(0.3275911f, x, 1.0f);
    float p = fmaf(t, 1.061405429f, -1.453152027f);
    p = fmaf(t, p, 1.421413741f);
    p = fmaf(t, p, -0.284496736f);
    p = fmaf(t, p, 0.254829592f);
    p *= t;
    return p * __expf(-x * x);
}

__device__ inline void cell_derived(const float* __restrict__ cell, int n,
                                    float& volume, float& eta, float M[3][3]) {
    float a00 = cell[0], a01 = cell[1], a02 = cell[2];
    float a10 = cell[3], a11 = cell[4], a12 = cell[5];
    float a20 = cell[6], a21 = cell[7], a22 = cell[8];
    float c00 = a11 * a22 - a12 * a21;
    float c01 = a12 * a20 - a10 * a22;
    float c02 = a10 * a21 - a11 * a20;
    float det = a00 * c00 + a01 * c01 + a02 * c02;
    volume = fabsf(det);
    eta = powf(volume * volume / (float)n, 1.0f / 6.0f) * INV_SQRT_2PI;
    float invdet = 1.0f / det;
    M[0][0] =  (a11 * a22 - a12 * a21) * invdet;
    M[0][1] = -(a01 * a22 - a02 * a21) * invdet;
    M[0][2] =  (a01 * a12 - a02 * a11) * invdet;
    M[1][0] = -(a10 * a22 - a12 * a20) * invdet;
    M[1][1] =  (a00 * a22 - a02 * a20) * invdet;
    M[1][2] = -(a00 * a12 - a02 * a10) * invdet;
    M[2][0] =  (a10 * a21 - a11 * a20) * invdet;
    M[2][1] = -(a00 * a21 - a01 * a20) * invdet;
    M[2][2] =  (a00 * a11 - a01 * a10) * invdet;
}

// Fused real+recip. Blocks [0, real_blocks) -> real-space triangular pairs;
// blocks [real_blocks, gridDim.x) -> reciprocal sum. Each block writes its
// scaled partial into partials[blockIdx.x] unconditionally (no init needed).
__global__ void ewald_fused_kernel(const float* __restrict__ pos,
                                   const float* __restrict__ cell,
                                   const float* __restrict__ charges,
                                   const float* __restrict__ sigma_table,
                                   const int* __restrict__ species,
                                   const int* __restrict__ p_nr,
                                   const int* __restrict__ p_nk,
                                   int n, int real_blocks,
                                   double* __restrict__ partials) {
    extern __shared__ float sm[];
    float* px = sm;
    float* py = sm + n;
    float* pz = sm + 2 * n;
    float* sq = sm + 3 * n;
    float* s2 = sm + 4 * n;
    float* red = sm + 5 * n;  // 8 floats

    for (int t = threadIdx.x; t < n; t += blockDim.x) {
        px[t] = pos[3 * t + 0];
        py[t] = pos[3 * t + 1];
        pz[t] = pos[3 * t + 2];
        sq[t] = charges[t];
        float s = sigma_table[species[t]];
        s2[t] = s * s;
    }
    __syncthreads();

    float vol, eta, M[3][3];
    cell_derived(cell, n, vol, eta, M);

    int lane = threadIdx.x & 63;
    int wave = threadIdx.x >> 6;
    float thr_acc = 0.0f;
    double scale;

    if (blockIdx.x < real_blocks) {
        // ---------- real space ----------
        int nr = p_nr[0];
        float cutoff = SQRT_2LOG * eta;
        float cut2 = cutoff * cutoff;
        float inv_s2eta = 1.0f / (1.41421356237f * eta);
        float c00 = cell[0], c01 = cell[1], c02 = cell[2];
        float c10 = cell[3], c11 = cell[4], c12 = cell[5];
        float c20 = cell[6], c21 = cell[7], c22 = cell[8];

        // Fast path: diagonal cell, cutoff inside one box, nr >= 1 ->
        // only the 2 nearest periodic images per axis can be < cutoff.
        float offdiag = fabsf(c01) + fabsf(c02) + fabsf(c10) +
                        fabsf(c12) + fabsf(c20) + fabsf(c21);
        bool fast = (offdiag == 0.0f) && (nr >= 1) &&
                    (cutoff < c00) && (cutoff < c11) && (cutoff < c22) &&
                    (c00 > 0.0f) && (c11 > 0.0f) && (c22 > 0.0f);

        long long T = (long long)n * (n + 1) / 2;
        long long p = (long long)blockIdx.x * blockDim.x + threadIdx.x;
        if (p < T) {
            // triangular decode: i >= j
            float fp = 8.0f * (float)p + 1.0f;
            int i = (int)((sqrtf(fp) - 1.0f) * 0.5f);
            while ((long long)i * (i + 1) / 2 > p) --i;
            while ((long long)(i + 1) * (i + 2) / 2 <= p) ++i;
            int j = (int)(p - (long long)i * (i + 1) / 2);

            float dx = px[j] - px[i];
            float dy = py[j] - py[i];
            float dz = pz[j] - pz[i];
            float gam2 = s2[i] + s2[j];
            float inv_s2gam = rsqrtf(2.0f * gam2);
            float pacc = 0.0f;

            if (fast) {
                // two image candidates per axis
                float w1x = fmaf(-rintf(dx / c00), c00, dx);
                float w1y = fmaf(-rintf(dy / c11), c11, dy);
                float w1z = fmaf(-rintf(dz / c22), c22, dz);
                float w2x = w1x - copysignf(c00, w1x);
                float w2y = w1y - copysignf(c11, w1y);
                float w2z = w1z - copysignf(c22, w1z);
                float xs[2] = {w1x, w2x};
                float ys[2] = {w1y, w2y};
                float zs[2] = {w1z, w2z};
                #pragma unroll
                for (int ax = 0; ax < 2; ++ax) {
                    #pragma unroll
                    for (int ay = 0; ay < 2; ++ay) {
                        #pragma unroll
                        for (int az = 0; az < 2; ++az) {
                            float ddx = xs[ax], ddy = ys[ay], ddz = zs[az];
                            float r2 = fmaf(ddx, ddx, fmaf(ddy, ddy, ddz * ddz));
                            bool in = (r2 > EPS2F) & (r2 < cut2);
                            if (__any(in)) {
                                float r2s = in ? r2 : 1.0f;
                                float m = in ? 1.0f : 0.0f;
                                float rinv = rsqrtf(r2s);
                                float r = r2s * rinv;
                                float v = (erfc_fast(r * inv_s2eta) -
                                           erfc_fast(r * inv_s2gam)) * rinv;
                                pacc = fmaf(v, m, pacc);
                            }
                        }
                    }
                }
            } else {
                for (int a = -nr; a <= nr; ++a)
                for (int b = -nr; b <= nr; ++b)
                for (int c = -nr; c <= nr; ++c) {
                    float ddx = dx + a * c00 + b * c10 + c * c20;
                    float ddy = dy + a * c01 + b * c11 + c * c21;
                    float ddz = dz + a * c02 + b * c12 + c * c22;
                    float r2 = fmaf(ddx, ddx, fmaf(ddy, ddy, ddz * ddz));
                    bool in = (r2 > EPS2F) & (r2 < cut2);
                    if (__any(in)) {
                        float r2s = in ? r2 : 1.0f;
                        float m = in ? 1.0f : 0.0f;
                        float rinv = rsqrtf(r2s);
                        float r = r2s * rinv;
                        float v = (erfc_fast(r * inv_s2eta) -
                                   erfc_fast(r * inv_s2gam)) * rinv;
                        pacc = fmaf(v, m, pacc);
                    }
                }
            }
            float w = (i == j) ? 1.0f : 2.0f;
            thr_acc = pacc * sq[i] * sq[j] * w;
        }
        scale = 0.5 * (double)COEF;
    } else {
        // ---------- reciprocal space ----------
        int nk = p_nk[0];
        int side = 2 * nk + 1;
        int K = side * side * side;
        float cutk = SQRT_2LOG / eta;
        float half_eta2 = 0.5f * eta * eta;

        int rb = blockIdx.x - real_blocks;
        int nrb = gridDim.x - real_blocks;
        int waves_per_block = blockDim.x >> 6;
        int gwave = rb * waves_per_block + wave;
        int nwaves = nrb * waves_per_block;

        for (int k = gwave; k < K; k += nwaves) {
            int a = k / (side * side) - nk;
            int rem = k % (side * side);
            int b = rem / side - nk;
            int c = rem % side - nk;
            float kx = TWO_PI * (M[0][0] * a + M[0][1] * b + M[0][2] * c);
            float ky = TWO_PI * (M[1][0] * a + M[1][1] * b + M[1][2] * c);
            float kz = TWO_PI * (M[2][0] * a + M[2][1] * b + M[2][2] * c);
            float k2 = fmaf(kx, kx, fmaf(ky, ky, kz * kz));
            float klen = sqrtf(k2);
            if (!(klen > 1e-8f && klen < cutk)) continue;
            float w = __expf(-half_eta2 * k2) / k2;
            float Sc = 0.0f, Ss = 0.0f;
            for (int i = lane; i < n; i += 64) {
                float th = fmaf(kx, px[i], fmaf(ky, py[i], kz * pz[i]));
                float sv, cv;
                __sincosf(th, &sv, &cv);
                float q = sq[i];
                Sc = fmaf(q, cv, Sc);
                Ss = fmaf(q, sv, Ss);
            }
            #pragma unroll
            for (int off = 32; off > 0; off >>= 1) {
                Sc += __shfl_down(Sc, off);
                Ss += __shfl_down(Ss, off);
            }
            if (lane == 0) thr_acc += w * (Sc * Sc + Ss * Ss);
        }
        scale = 0.5 * (double)COEF * (4.0 * 3.14159265358979323846 / (double)vol);
    }

    // block reduce
    float v = thr_acc;
    #pragma unroll
    for (int off = 32; off > 0; off >>= 1) v += __shfl_down(v, off);
    if (lane == 0) red[wave] = v;
    __syncthreads();
    if (threadIdx.x == 0) {
        float tot = 0.0f;
        int nw = blockDim.x >> 6;
        for (int w = 0; w < nw; ++w) tot += red[w];
        partials[blockIdx.x] = (double)tot * scale;
    }
}

// Reduce block partials + self term, write the scalar output.
__global__ void ewald_final_kernel(const float* __restrict__ cell,
                                   const float* __restrict__ charges,
                                   const float* __restrict__ sigma_table,
                                   const int* __restrict__ species,
                                   int n, int nparts,
                                   const double* __restrict__ partials,
                                   float* __restrict__ out) {
    __shared__ double redd[8];
    float vol, eta, M[3][3];
    cell_derived(cell, n, vol, eta, M);

    double dsum = 0.0;
    for (int i = threadIdx.x; i < nparts; i += blockDim.x)
        dsum += partials[i];
    for (int i = threadIdx.x; i < n; i += blockDim.x) {
        float s = sigma_table[species[i]];
        float q = charges[i];
        float diag = -SQRT_2_OVER_PI / eta + INV_SQRT_PI / s;
        dsum += (double)(0.5f * COEF * q * q * diag);
    }
    double v = dsum;
    #pragma unroll
    for (int off = 32; off > 0; off >>= 1) v += __shfl_down(v, off);
    int wave = threadIdx.x >> 6, lane = threadIdx.x & 63;
    if (lane == 0) redd[wave] = v;
    __syncthreads();
    if (threadIdx.x == 0) {
        double tot = 0.0;
        int nw = blockDim.x >> 6;
        for (int w = 0; w < nw; ++w) tot += redd[w];
        out[0] = (float)tot;
    }
}

extern "C" void kernel_launch(void* const* d_in, const int* in_sizes, int n_in,
                              void* d_out, int out_size, void* d_ws, size_t ws_size,
                              hipStream_t stream) {
    const float* pos         = (const float*)d_in[0];
    const float* cell        = (const float*)d_in[1];
    const float* charges     = (const float*)d_in[2];
    const float* sigma_table = (const float*)d_in[3];
    const int*   species     = (const int*)d_in[4];
    const int*   p_nr        = (const int*)d_in[5];
    const int*   p_nk        = (const int*)d_in[6];
    int n = in_sizes[0] / 3;

    double* partials = (double*)d_ws;
    float* out = (float*)d_out;

    long long T = (long long)n * (n + 1) / 2;
    int real_blocks = (int)((T + 255) / 256);   // 1154 for n=768
    int recip_blocks = 308;
    int total_blocks = real_blocks + recip_blocks;
    size_t sm_bytes = (size_t)(5 * n + 16) * sizeof(float);

    ewald_fused_kernel<<<total_blocks, 256, sm_bytes, stream>>>(
        pos, cell, charges, sigma_table, species, p_nr, p_nk,
        n, real_blocks, partials);

    ewald_final_kernel<<<1, 256, 0, stream>>>(
        cell, charges, sigma_table, species, n, total_blocks, partials, out);
}